// Round 3
// baseline (92.590 us; speedup 1.0000x reference)
//
#include <hip/hip_runtime.h>

// ColorDenseCRFLoss via MFMA:
// out = -1e-7/4 * sum_{n,p,q} exp(-0.5*||f_p-f_q||^2) * (seg_p . seg_q)
// Both inner products computed by mfma_f32_16x16x32_bf16 on augmented
// per-pixel bf16 vectors (hi/lo split => ~fp32 product precision).

#define N_BATCH 4
#define IH 128
#define IW 128
#define P 4096   // 64x64 downsampled pixels per batch
#define KC 21

using short8  = __attribute__((ext_vector_type(8))) short;
using floatx4 = __attribute__((ext_vector_type(4))) float;

static constexpr float INV_SIGMA = 1.0f / 15.0f;
static constexpr float LOG2E     = 1.4426950408889634f;
static constexpr float OUT_SCALE = -1e-7f / 4.0f;

// ws layout (bytes):
//   [0,64)      zero page (16B used, read by padded quads)
//   argA: N*P rows x 16 bf16 (32B each)
//   argB: N*P rows x 16 bf16 (32B each)
//   seg : N*P rows x 24 bf16 (48B each)
#define ZP_OFF   0
#define ARGA_OFF 64
#define ARGB_OFF (ARGA_OFF + N_BATCH * P * 32)
#define SEG_OFF  (ARGB_OFF + N_BATCH * P * 32)

#define NFEAT (N_BATCH * P)          // 16384 feats/args threads
#define NSEG  (N_BATCH * KC * P)     // 344064 seg-pool threads

__device__ __forceinline__ ushort f2bf(float x) {  // RNE float->bf16 bits
    unsigned u = __builtin_bit_cast(unsigned, x);
    unsigned r = (u + 0x7FFFu + ((u >> 16) & 1u)) >> 16;
    return (ushort)r;
}
__device__ __forceinline__ float bf2f(ushort h) {
    return __builtin_bit_cast(float, (unsigned)h << 16);
}

// Parallel prep: threads [0,NFEAT) build per-pixel arg vectors (and zero the
// seg pad + zero page + out); threads [NFEAT, NFEAT+NSEG) each pool ONE
// (batch, channel, pixel) -> one bf16 store. 1408 blocks x 256.
__global__ void crf_prep(const float* __restrict__ img,
                         const float* __restrict__ seg,
                         char* __restrict__ wsb,
                         float* __restrict__ out)
{
    int t = blockIdx.x * blockDim.x + threadIdx.x;
    if (t < NFEAT) {
        if (t == 0) out[0] = 0.0f;
        if (t < 16) ((float*)(wsb + ZP_OFF))[t] = 0.0f;  // zero page

        int n = t >> 12;
        int p = t & (P - 1);
        int y = p >> 6, x = p & 63;

        const float* ib = img + (size_t)n * 3 * IH * IW + (size_t)(2 * y) * IW + 2 * x;
        float f0 = ib[0] * INV_SIGMA;
        float f1 = ib[IH * IW] * INV_SIGMA;
        float f2 = ib[2 * IH * IW] * INV_SIGMA;
        float h = 0.5f * (f0 * f0 + f1 * f1 + f2 * f2);

        // A-side color, pre-scaled by log2(e); hi/lo bf16 split
        float fa0 = f0 * LOG2E, fa1 = f1 * LOG2E, fa2 = f2 * LOG2E;
        ushort ah0 = f2bf(fa0), ah1 = f2bf(fa1), ah2 = f2bf(fa2);
        ushort al0 = f2bf(fa0 - bf2f(ah0));
        ushort al1 = f2bf(fa1 - bf2f(ah1));
        ushort al2 = f2bf(fa2 - bf2f(ah2));
        float nhL = -h * LOG2E;
        ushort nhh = f2bf(nhL), nhl = f2bf(nhL - bf2f(nhh));
        // B-side color, unscaled; hi/lo split
        ushort bh0 = f2bf(f0), bh1 = f2bf(f1), bh2 = f2bf(f2);
        ushort bl0 = f2bf(f0 - bf2f(bh0));
        ushort bl1 = f2bf(f1 - bf2f(bh1));
        ushort bl2 = f2bf(f2 - bf2f(bh2));
        float hL = h * LOG2E;
        ushort hbh = f2bf(hL), hbl = f2bf(hL - bf2f(hbh));

        const ushort ONE = 0x3F80, NEG1 = 0xBF80;
        // dot(argA_p, argB_q) = log2e * (f_p.f_q - h_p - h_q)
        ushort rA[16] = {ah0, ah1, ah2, ah0, ah1, ah2, al0, al1, al2, al0, al1, al2,
                         nhh, nhl, NEG1, NEG1};
        ushort rB[16] = {bh0, bh1, bh2, bl0, bl1, bl2, bh0, bh1, bh2, bl0, bl1, bl2,
                         ONE, ONE, hbh, hbl};

        short8 vA0, vA1, vB0, vB1;
#pragma unroll
        for (int j = 0; j < 8; ++j) {
            vA0[j] = (short)rA[j];     vA1[j] = (short)rA[8 + j];
            vB0[j] = (short)rB[j];     vB1[j] = (short)rB[8 + j];
        }
        short8* dA = (short8*)(wsb + ARGA_OFF + (size_t)t * 32);
        dA[0] = vA0; dA[1] = vA1;
        short8* dB = (short8*)(wsb + ARGB_OFF + (size_t)t * 32);
        dB[0] = vB0; dB[1] = vB1;

        // zero the seg pad (k = 21..23) for this pixel
        char* sp = wsb + SEG_OFF + (size_t)t * 48;
        *(ushort*)(sp + 42) = 0;
        *(uint*)(sp + 44) = 0;
    } else if (t < NFEAT + NSEG) {
        int u = t - NFEAT;           // ((n*21 + k) << 12) | p
        int p = u & (P - 1);
        int nk = u >> 12;            // n*21 + k
        int n = nk / 21;
        int k = nk - n * 21;
        int y = p >> 6, x = p & 63;

        const float* s = seg + (size_t)nk * IH * IW + (size_t)(2 * y) * IW + 2 * x;
        float v = 0.25f * ((s[0] + s[1]) + (s[IW] + s[IW + 1]));
        *(ushort*)(wsb + SEG_OFF + (size_t)(n * P + p) * 48 + k * 2) = f2bf(v);
    }
}

// Each wave: 4 p-tiles (64 rows, A frags in regs) x 8 q-tiles (streamed,
// 1-deep prefetch). Per q-tile: 8 MFMAs + 16 x (exp2, fmac).
__global__ __launch_bounds__(256) void crf_pair(const char* __restrict__ wsb,
                                                float* __restrict__ out)
{
    int n = blockIdx.z;
    int wave = threadIdx.x >> 6;
    int lane = threadIdx.x & 63;
    int quad = lane >> 4;
    int l16  = lane & 15;

    const char* argA = wsb + ARGA_OFF + (size_t)n * P * 32;
    const char* argB = wsb + ARGB_OFF + (size_t)n * P * 32;
    const char* segT = wsb + SEG_OFF  + (size_t)n * P * 48;
    const char* zp   = wsb + ZP_OFF;

    // A fragments: 4 p-tiles, rows prow..prow+63
    int prow = blockIdx.y * 64;
    short8 aArg[4], aSeg[4];
#pragma unroll
    for (int i = 0; i < 4; ++i) {
        int m = prow + i * 16 + l16;
        aArg[i] = *(const short8*)(quad < 2 ? argA + m * 32 + quad * 16 : zp);
        aSeg[i] = *(const short8*)(quad < 3 ? segT + m * 48 + quad * 16 : zp);
    }

    float part = 0.0f;
    int qt0 = blockIdx.x * 32 + wave;          // q-tiles qt0 + 4t, t=0..7
    int q = qt0 * 16 + l16;
    short8 bArg = *(const short8*)(quad < 2 ? argB + q * 32 + quad * 16 : zp);
    short8 bSeg = *(const short8*)(quad < 3 ? segT + q * 48 + quad * 16 : zp);

    for (int t = 0; t < 8; ++t) {
        int qn = (t < 7) ? (qt0 + 4 * (t + 1)) * 16 + l16 : q;
        short8 bArgN = *(const short8*)(quad < 2 ? argB + qn * 32 + quad * 16 : zp);
        short8 bSegN = *(const short8*)(quad < 3 ? segT + qn * 48 + quad * 16 : zp);

        floatx4 zero = {0.0f, 0.0f, 0.0f, 0.0f};
#pragma unroll
        for (int i = 0; i < 4; ++i) {
            floatx4 g  = __builtin_amdgcn_mfma_f32_16x16x32_bf16(aSeg[i], bSeg, zero, 0, 0, 0);
            floatx4 ar = __builtin_amdgcn_mfma_f32_16x16x32_bf16(aArg[i], bArg, zero, 0, 0, 0);
#pragma unroll
            for (int j = 0; j < 4; ++j) {
                float e = __builtin_amdgcn_exp2f(ar[j]);  // arg<=0 up to ~5e-3 rounding
                part += e * g[j];
            }
        }
        bArg = bArgN; bSeg = bSegN;
    }

    // reduce: wave -> block -> global
#pragma unroll
    for (int off = 32; off > 0; off >>= 1)
        part += __shfl_down(part, off, 64);
    __shared__ float wsum[4];
    if (lane == 0) wsum[wave] = part;
    __syncthreads();
    if (threadIdx.x == 0)
        atomicAdd(out, ((wsum[0] + wsum[1]) + (wsum[2] + wsum[3])) * OUT_SCALE);
}

extern "C" void kernel_launch(void* const* d_in, const int* in_sizes, int n_in,
                              void* d_out, int out_size, void* d_ws, size_t ws_size,
                              hipStream_t stream)
{
    const float* images = (const float*)d_in[0];   // [4,3,128,128]
    const float* segm   = (const float*)d_in[1];   // [4,21,128,128]
    float* out = (float*)d_out;                    // [1]
    char* wsb = (char*)d_ws;                       // ~1.79 MB used

    int prep_threads = NFEAT + NSEG;
    crf_prep<<<dim3((prep_threads + 255) / 256), dim3(256), 0, stream>>>(
        images, segm, wsb, out);
    crf_pair<<<dim3(8, 64, N_BATCH), dim3(256), 0, stream>>>(wsb, out);
}